// Round 1
// baseline (82.685 us; speedup 1.0000x reference)
//
#include <hip/hip_runtime.h>
#include <hip/hip_bf16.h>

#define BB 2
#define NN 4096
#define LL 256
#define DD 2048
#define CC 6
#define EPSF 1e-6f

// ---------------------------------------------------------------------------
// K1: cluster_logits = text_emb . Wc^T ; softmax over C  -> cw (B,L,C)
// one block per (b,l) row
__global__ __launch_bounds__(256) void k_cluster(const float* __restrict__ te,
                                                 const float* __restrict__ Wc,
                                                 float* __restrict__ cw) {
    const int row = blockIdx.x;              // b*LL + l
    const float* trow = te + (size_t)row * DD;
    float p[CC];
#pragma unroll
    for (int c = 0; c < CC; ++c) p[c] = 0.f;
    for (int d = threadIdx.x; d < DD; d += 256) {
        float xv = trow[d];
#pragma unroll
        for (int c = 0; c < CC; ++c) p[c] = fmaf(xv, Wc[c * DD + d], p[c]);
    }
#pragma unroll
    for (int c = 0; c < CC; ++c)
        for (int off = 32; off; off >>= 1) p[c] += __shfl_down(p[c], off);
    __shared__ float sred[4][CC];
    const int lane = threadIdx.x & 63, wid = threadIdx.x >> 6;
    if (lane == 0) {
#pragma unroll
        for (int c = 0; c < CC; ++c) sred[wid][c] = p[c];
    }
    __syncthreads();
    if (threadIdx.x == 0) {
        float lg[CC], m = -1e30f;
#pragma unroll
        for (int c = 0; c < CC; ++c) {
            lg[c] = sred[0][c] + sred[1][c] + sred[2][c] + sred[3][c];
            m = fmaxf(m, lg[c]);
        }
        float s = 0.f;
#pragma unroll
        for (int c = 0; c < CC; ++c) { lg[c] = __expf(lg[c] - m); s += lg[c]; }
        float inv = 1.f / s;
#pragma unroll
        for (int c = 0; c < CC; ++c) cw[row * CC + c] = lg[c] * inv;
    }
}

// ---------------------------------------------------------------------------
// K2: concept_reps[b,c,d] = sum_l cw[b,l,c]*te[b,l,d]   -> cr (B,C,D)
// grid = B * (D/256); each thread one d, cw row-block staged in LDS
__global__ __launch_bounds__(256) void k_creps(const float* __restrict__ te,
                                               const float* __restrict__ cw,
                                               float* __restrict__ cr) {
    const int blocksPerB = DD / 256;         // 8
    const int b = blockIdx.x / blocksPerB;
    const int d = (blockIdx.x % blocksPerB) * 256 + threadIdx.x;
    __shared__ float scw[LL * CC];
    for (int i = threadIdx.x; i < LL * CC; i += 256) scw[i] = cw[b * LL * CC + i];
    __syncthreads();
    float acc[CC];
#pragma unroll
    for (int c = 0; c < CC; ++c) acc[c] = 0.f;
    const float* tb = te + (size_t)b * LL * DD + d;
    for (int l = 0; l < LL; ++l) {
        float xv = tb[(size_t)l * DD];
#pragma unroll
        for (int c = 0; c < CC; ++c) acc[c] = fmaf(scw[l * CC + c], xv, acc[c]);
    }
#pragma unroll
    for (int c = 0; c < CC; ++c) cr[((size_t)b * CC + c) * DD + d] = acc[c];
}

// ---------------------------------------------------------------------------
// K3: v[b,c,e] = sum_d cr[b,c,d]*Wv[e,d]; then blend-softmax + variance gate
//     fused[b,e] = sum_c blend[c]*v + gate*var_c(v)*0.3      -> fused (B,D)
// one wave per 4 e-columns; Wv rows read once, coalesced float4
__global__ __launch_bounds__(256) void k_vfuse(const float* __restrict__ cr,
                                               const float* __restrict__ Wv,
                                               const float* __restrict__ blendw,
                                               const float* __restrict__ sgate,
                                               const int* __restrict__ issur,
                                               float* __restrict__ fused) {
    const int wid = blockIdx.x * 4 + (threadIdx.x >> 6);
    const int lane = threadIdx.x & 63;
    const int e0 = wid * 4;
    float acc[BB][CC][4];
#pragma unroll
    for (int b = 0; b < BB; ++b)
#pragma unroll
        for (int c = 0; c < CC; ++c)
#pragma unroll
            for (int j = 0; j < 4; ++j) acc[b][c][j] = 0.f;

    for (int it = 0; it < DD / 256; ++it) {
        const int d = it * 256 + lane * 4;
        float4 w[4];
#pragma unroll
        for (int j = 0; j < 4; ++j)
            w[j] = *(const float4*)(Wv + (size_t)(e0 + j) * DD + d);
#pragma unroll
        for (int b = 0; b < BB; ++b)
#pragma unroll
            for (int c = 0; c < CC; ++c) {
                float4 cv = *(const float4*)(cr + ((size_t)b * CC + c) * DD + d);
#pragma unroll
                for (int j = 0; j < 4; ++j)
                    acc[b][c][j] += cv.x * w[j].x + cv.y * w[j].y +
                                    cv.z * w[j].z + cv.w * w[j].w;
            }
    }
#pragma unroll
    for (int b = 0; b < BB; ++b)
#pragma unroll
        for (int c = 0; c < CC; ++c)
#pragma unroll
            for (int j = 0; j < 4; ++j) {
                float v = acc[b][c][j];
                for (int off = 32; off; off >>= 1) v += __shfl_down(v, off);
                acc[b][c][j] = v;
            }
    if (lane == 0) {
        float bw[CC], m = -1e30f;
#pragma unroll
        for (int c = 0; c < CC; ++c) { bw[c] = blendw[c]; m = fmaxf(m, bw[c]); }
        float s = 0.f;
#pragma unroll
        for (int c = 0; c < CC; ++c) { bw[c] = __expf(bw[c] - m); s += bw[c]; }
        float inv = 1.f / s;
#pragma unroll
        for (int c = 0; c < CC; ++c) bw[c] *= inv;
        const float gate = 1.f / (1.f + __expf(-sgate[0]));
        const int sur = issur[0];
#pragma unroll
        for (int b = 0; b < BB; ++b)
#pragma unroll
            for (int j = 0; j < 4; ++j) {
                float f = 0.f, mean = 0.f;
#pragma unroll
                for (int c = 0; c < CC; ++c) {
                    f = fmaf(bw[c], acc[b][c][j], f);
                    mean += acc[b][c][j];
                }
                mean *= (1.f / CC);
                float var = 0.f;
#pragma unroll
                for (int c = 0; c < CC; ++c) {
                    float dv = acc[b][c][j] - mean;
                    var = fmaf(dv, dv, var);
                }
                var *= (1.f / (CC - 1));     // ddof=1
                if (sur) f = fmaf(gate * var, 0.3f, f);
                fused[b * DD + e0 + j] = f;
            }
    }
}

// ---------------------------------------------------------------------------
// K4: RMSNorm of fused (per b over D) -> normed (B,D)
__global__ __launch_bounds__(256) void k_rms(const float* __restrict__ fused,
                                             const float* __restrict__ nw,
                                             float* __restrict__ normed) {
    const int b = blockIdx.x;
    float ss = 0.f;
    for (int d = threadIdx.x; d < DD; d += 256) {
        float v = fused[b * DD + d];
        ss = fmaf(v, v, ss);
    }
    for (int off = 32; off; off >>= 1) ss += __shfl_down(ss, off);
    __shared__ float sred[4];
    __shared__ float sscale;
    const int lane = threadIdx.x & 63, wid = threadIdx.x >> 6;
    if (lane == 0) sred[wid] = ss;
    __syncthreads();
    if (threadIdx.x == 0) {
        float tot = sred[0] + sred[1] + sred[2] + sred[3];
        sscale = rsqrtf(tot * (1.f / DD) + EPSF);
    }
    __syncthreads();
    const float scale = sscale;
    for (int d = threadIdx.x; d < DD; d += 256)
        normed[b * DD + d] = fused[b * DD + d] * scale * nw[d];
}

// ---------------------------------------------------------------------------
// K5: o[b,e] = sum_d normed[b,d]*Wo[e,d]  -> o (B,D)
__global__ __launch_bounds__(256) void k_outproj(const float* __restrict__ normed,
                                                 const float* __restrict__ Wo,
                                                 float* __restrict__ o) {
    const int wid = blockIdx.x * 4 + (threadIdx.x >> 6);
    const int lane = threadIdx.x & 63;
    const int e0 = wid * 4;
    float acc[BB][4];
#pragma unroll
    for (int b = 0; b < BB; ++b)
#pragma unroll
        for (int j = 0; j < 4; ++j) acc[b][j] = 0.f;
    for (int it = 0; it < DD / 256; ++it) {
        const int d = it * 256 + lane * 4;
        float4 w[4];
#pragma unroll
        for (int j = 0; j < 4; ++j)
            w[j] = *(const float4*)(Wo + (size_t)(e0 + j) * DD + d);
#pragma unroll
        for (int b = 0; b < BB; ++b) {
            float4 nv = *(const float4*)(normed + (size_t)b * DD + d);
#pragma unroll
            for (int j = 0; j < 4; ++j)
                acc[b][j] += nv.x * w[j].x + nv.y * w[j].y +
                             nv.z * w[j].z + nv.w * w[j].w;
        }
    }
#pragma unroll
    for (int b = 0; b < BB; ++b)
#pragma unroll
        for (int j = 0; j < 4; ++j) {
            float v = acc[b][j];
            for (int off = 32; off; off >>= 1) v += __shfl_down(v, off);
            if (lane == 0) o[b * DD + e0 + j] = v;
        }
}

// ---------------------------------------------------------------------------
// K6: out[b,n,e] = x[b,n,e] + o[b,e]   (float4, grid-stride)
__global__ __launch_bounds__(256) void k_add(const float* __restrict__ x,
                                             const float* __restrict__ o,
                                             float* __restrict__ out) {
    const size_t total4 = (size_t)BB * NN * DD / 4;   // 2^22
    const float4* x4 = (const float4*)x;
    const float4* o4 = (const float4*)o;
    float4* out4 = (float4*)out;
    for (size_t f = (size_t)blockIdx.x * 256 + threadIdx.x; f < total4;
         f += (size_t)gridDim.x * 256) {
        const int e4 = (int)(f & (DD / 4 - 1));
        const int b = (int)(f >> 21);                 // NN*DD/4 = 2^21
        float4 xv = x4[f];
        float4 ov = o4[b * (DD / 4) + e4];
        float4 r;
        r.x = xv.x + ov.x; r.y = xv.y + ov.y;
        r.z = xv.z + ov.z; r.w = xv.w + ov.w;
        out4[f] = r;
    }
}

extern "C" void kernel_launch(void* const* d_in, const int* in_sizes, int n_in,
                              void* d_out, int out_size, void* d_ws, size_t ws_size,
                              hipStream_t stream) {
    const float* x  = (const float*)d_in[0];
    const float* te = (const float*)d_in[1];
    const float* Wc = (const float*)d_in[2];
    // d_in[3] = Wq, d_in[4] = Wk : unused (softmax over a single key)
    const float* Wv = (const float*)d_in[5];
    const float* Wo = (const float*)d_in[6];
    const float* bw = (const float*)d_in[7];
    const float* sg = (const float*)d_in[8];
    const float* nw = (const float*)d_in[9];
    const int* isur = (const int*)d_in[10];
    float* out = (float*)d_out;

    float* ws     = (float*)d_ws;
    float* cw     = ws;                       // B*L*C  = 3072
    float* cr     = ws + 4096;                // B*C*D  = 24576
    float* fused  = ws + 4096 + 24576;        // B*D    = 4096
    float* normed = fused + 4096;             // B*D
    float* o      = normed + 4096;            // B*D

    hipLaunchKernelGGL(k_cluster, dim3(BB * LL), dim3(256), 0, stream, te, Wc, cw);
    hipLaunchKernelGGL(k_creps,   dim3(BB * (DD / 256)), dim3(256), 0, stream, te, cw, cr);
    hipLaunchKernelGGL(k_vfuse,   dim3(DD / 16), dim3(256), 0, stream, cr, Wv, bw, sg, isur, fused);
    hipLaunchKernelGGL(k_rms,     dim3(BB), dim3(256), 0, stream, fused, nw, normed);
    hipLaunchKernelGGL(k_outproj, dim3(DD / 16), dim3(256), 0, stream, normed, Wo, o);
    hipLaunchKernelGGL(k_add,     dim3(2048), dim3(256), 0, stream, x, o, out);
}

// Round 2
// 52.224 us; speedup vs baseline: 1.5833x; 1.5833x over previous
//
#include <hip/hip_runtime.h>
#include <hip/hip_bf16.h>

#define BB 2
#define NN 4096
#define LL 256
#define DD 2048
#define CC 6
#define EPSF 1e-6f

__device__ __forceinline__ float dot4(float4 a, float4 b) {
    return a.x * b.x + a.y * b.y + a.z * b.z + a.w * b.w;
}

// ---------------------------------------------------------------------------
// K1: cluster_logits = text_emb . Wc^T ; softmax over C  -> cw (B,L,C)
// one block per (b,l) row, float4 loads
__global__ __launch_bounds__(256) void k_cluster(const float* __restrict__ te,
                                                 const float* __restrict__ Wc,
                                                 float* __restrict__ cw) {
    const int row = blockIdx.x;              // b*LL + l
    const float4* t4 = (const float4*)(te + (size_t)row * DD);
    float p[CC];
#pragma unroll
    for (int c = 0; c < CC; ++c) p[c] = 0.f;
#pragma unroll
    for (int it = 0; it < DD / 4 / 256; ++it) {   // 2 iters
        const int i = it * 256 + threadIdx.x;
        const float4 xv = t4[i];
#pragma unroll
        for (int c = 0; c < CC; ++c) {
            const float4 wv = ((const float4*)(Wc + (size_t)c * DD))[i];
            p[c] += dot4(xv, wv);
        }
    }
#pragma unroll
    for (int c = 0; c < CC; ++c)
        for (int off = 32; off; off >>= 1) p[c] += __shfl_down(p[c], off);
    __shared__ float sred[4][CC];
    const int lane = threadIdx.x & 63, wid = threadIdx.x >> 6;
    if (lane == 0) {
#pragma unroll
        for (int c = 0; c < CC; ++c) sred[wid][c] = p[c];
    }
    __syncthreads();
    if (threadIdx.x == 0) {
        float lg[CC], m = -1e30f;
#pragma unroll
        for (int c = 0; c < CC; ++c) {
            lg[c] = sred[0][c] + sred[1][c] + sred[2][c] + sred[3][c];
            m = fmaxf(m, lg[c]);
        }
        float s = 0.f;
#pragma unroll
        for (int c = 0; c < CC; ++c) { lg[c] = __expf(lg[c] - m); s += lg[c]; }
        float inv = 1.f / s;
#pragma unroll
        for (int c = 0; c < CC; ++c) cw[row * CC + c] = lg[c] * inv;
    }
}

// ---------------------------------------------------------------------------
// K2: concept_reps[b,c,d] = sum_l cw[b,l,c]*te[b,l,d]   -> cr (B,C,D)
// grid = B*32 blocks; block covers d-slice of 64, 4 l-chunks across waves
__global__ __launch_bounds__(256) void k_creps(const float* __restrict__ te,
                                               const float* __restrict__ cw,
                                               float* __restrict__ cr) {
    const int b = blockIdx.x >> 5;
    const int d0 = (blockIdx.x & 31) * 64;
    __shared__ float scw[LL * CC];                       // 6 KB
    for (int i = threadIdx.x; i < LL * CC; i += 256) scw[i] = cw[b * LL * CC + i];
    __syncthreads();
    const int dl = threadIdx.x & 63;                     // d within slice
    const int lc = threadIdx.x >> 6;                     // l-chunk 0..3
    float acc[CC];
#pragma unroll
    for (int c = 0; c < CC; ++c) acc[c] = 0.f;
    const float* tb = te + ((size_t)b * LL + lc * 64) * DD + d0 + dl;
    for (int l = 0; l < 64; ++l) {
        const float xv = tb[(size_t)l * DD];
        const int gl = lc * 64 + l;
#pragma unroll
        for (int c = 0; c < CC; ++c) acc[c] = fmaf(scw[gl * CC + c], xv, acc[c]);
    }
    __shared__ float sacc[4][64][CC];                    // 6 KB
#pragma unroll
    for (int c = 0; c < CC; ++c) sacc[lc][dl][c] = acc[c];
    __syncthreads();
    if (threadIdx.x < 64) {
#pragma unroll
        for (int c = 0; c < CC; ++c) {
            const float s = sacc[0][threadIdx.x][c] + sacc[1][threadIdx.x][c] +
                            sacc[2][threadIdx.x][c] + sacc[3][threadIdx.x][c];
            cr[((size_t)b * CC + c) * DD + d0 + threadIdx.x] = s;
        }
    }
}

// ---------------------------------------------------------------------------
// K3: v[b,c,e] = sum_d cr[b,c,d]*Wv[e,d]; blend-softmax + unbiased-var gate
//     fused[b,e] -> (B,D).  One WAVE per e-column; grid 512 blocks.
__global__ __launch_bounds__(256) void k_vfuse(const float* __restrict__ cr,
                                               const float* __restrict__ Wv,
                                               const float* __restrict__ blendw,
                                               const float* __restrict__ sgate,
                                               const int* __restrict__ issur,
                                               float* __restrict__ fused) {
    const int e = blockIdx.x * 4 + (threadIdx.x >> 6);
    const int lane = threadIdx.x & 63;
    float acc[BB][CC];
#pragma unroll
    for (int b = 0; b < BB; ++b)
#pragma unroll
        for (int c = 0; c < CC; ++c) acc[b][c] = 0.f;
#pragma unroll
    for (int it = 0; it < DD / 256; ++it) {              // 8 iters
        const int d = it * 256 + lane * 4;
        const float4 wv = *(const float4*)(Wv + (size_t)e * DD + d);
#pragma unroll
        for (int b = 0; b < BB; ++b)
#pragma unroll
            for (int c = 0; c < CC; ++c) {
                const float4 cv = *(const float4*)(cr + ((size_t)b * CC + c) * DD + d);
                acc[b][c] += dot4(cv, wv);
            }
    }
#pragma unroll
    for (int b = 0; b < BB; ++b)
#pragma unroll
        for (int c = 0; c < CC; ++c)
            for (int off = 32; off; off >>= 1) acc[b][c] += __shfl_down(acc[b][c], off);
    if (lane == 0) {
        float bw[CC], m = -1e30f;
#pragma unroll
        for (int c = 0; c < CC; ++c) { bw[c] = blendw[c]; m = fmaxf(m, bw[c]); }
        float s = 0.f;
#pragma unroll
        for (int c = 0; c < CC; ++c) { bw[c] = __expf(bw[c] - m); s += bw[c]; }
        const float inv = 1.f / s;
#pragma unroll
        for (int c = 0; c < CC; ++c) bw[c] *= inv;
        const float gate = 1.f / (1.f + __expf(-sgate[0]));
        const int sur = issur[0];
#pragma unroll
        for (int b = 0; b < BB; ++b) {
            float f = 0.f, mean = 0.f;
#pragma unroll
            for (int c = 0; c < CC; ++c) {
                f = fmaf(bw[c], acc[b][c], f);
                mean += acc[b][c];
            }
            mean *= (1.f / CC);
            float var = 0.f;
#pragma unroll
            for (int c = 0; c < CC; ++c) {
                const float dv = acc[b][c] - mean;
                var = fmaf(dv, dv, var);
            }
            var *= (1.f / (CC - 1));                     // ddof=1
            if (sur) f = fmaf(gate * var, 0.3f, f);
            fused[b * DD + e] = f;
        }
    }
}

// ---------------------------------------------------------------------------
// K4: RMSNorm (recomputed per block from L2-resident fused) + out-proj.
//     o[b,e] = sum_d fused[b,d]*scale_b*nw[d]*Wo[e,d].  One wave per e.
__global__ __launch_bounds__(256) void k_rmsout(const float* __restrict__ fused,
                                                const float* __restrict__ nw,
                                                const float* __restrict__ Wo,
                                                float* __restrict__ o) {
    const int lane = threadIdx.x & 63, wid = threadIdx.x >> 6;
    // --- per-block recompute of the two RMS scales (cheap, L2 reads) ---
    float ss[BB];
#pragma unroll
    for (int b = 0; b < BB; ++b) ss[b] = 0.f;
#pragma unroll
    for (int k = 0; k < DD / 256; ++k) {
        const int d = k * 256 + threadIdx.x;
#pragma unroll
        for (int b = 0; b < BB; ++b) {
            const float v = fused[b * DD + d];
            ss[b] = fmaf(v, v, ss[b]);
        }
    }
#pragma unroll
    for (int b = 0; b < BB; ++b)
        for (int off = 32; off; off >>= 1) ss[b] += __shfl_down(ss[b], off);
    __shared__ float sred[4][BB];
    __shared__ float sscale[BB];
    if (lane == 0) {
#pragma unroll
        for (int b = 0; b < BB; ++b) sred[wid][b] = ss[b];
    }
    __syncthreads();
    if (threadIdx.x == 0) {
#pragma unroll
        for (int b = 0; b < BB; ++b) {
            const float tot = sred[0][b] + sred[1][b] + sred[2][b] + sred[3][b];
            sscale[b] = rsqrtf(tot * (1.f / DD) + EPSF);
        }
    }
    __syncthreads();
    // --- GEMV: one wave per e-column ---
    const int e = blockIdx.x * 4 + wid;
    float acc[BB];
#pragma unroll
    for (int b = 0; b < BB; ++b) acc[b] = 0.f;
#pragma unroll
    for (int it = 0; it < DD / 256; ++it) {
        const int d = it * 256 + lane * 4;
        const float4 wv = *(const float4*)(Wo + (size_t)e * DD + d);
        const float4 nv = *(const float4*)(nw + d);
        float4 t;
        t.x = wv.x * nv.x; t.y = wv.y * nv.y; t.z = wv.z * nv.z; t.w = wv.w * nv.w;
#pragma unroll
        for (int b = 0; b < BB; ++b) {
            const float4 fv = *(const float4*)(fused + (size_t)b * DD + d);
            acc[b] += dot4(fv, t);
        }
    }
#pragma unroll
    for (int b = 0; b < BB; ++b) {
        for (int off = 32; off; off >>= 1) acc[b] += __shfl_down(acc[b], off);
        if (lane == 0) o[b * DD + e] = acc[b] * sscale[b];
    }
}

// ---------------------------------------------------------------------------
// K5: out[b,n,e] = x[b,n,e] + o[b,e]   (float4, grid-stride)
__global__ __launch_bounds__(256) void k_add(const float* __restrict__ x,
                                             const float* __restrict__ o,
                                             float* __restrict__ out) {
    const size_t total4 = (size_t)BB * NN * DD / 4;   // 2^22
    const float4* x4 = (const float4*)x;
    const float4* o4 = (const float4*)o;
    float4* out4 = (float4*)out;
    for (size_t f = (size_t)blockIdx.x * 256 + threadIdx.x; f < total4;
         f += (size_t)gridDim.x * 256) {
        const int e4 = (int)(f & (DD / 4 - 1));
        const int b = (int)(f >> 21);                 // NN*DD/4 = 2^21
        const float4 xv = x4[f];
        const float4 ov = o4[b * (DD / 4) + e4];
        float4 r;
        r.x = xv.x + ov.x; r.y = xv.y + ov.y;
        r.z = xv.z + ov.z; r.w = xv.w + ov.w;
        out4[f] = r;
    }
}

extern "C" void kernel_launch(void* const* d_in, const int* in_sizes, int n_in,
                              void* d_out, int out_size, void* d_ws, size_t ws_size,
                              hipStream_t stream) {
    const float* x  = (const float*)d_in[0];
    const float* te = (const float*)d_in[1];
    const float* Wc = (const float*)d_in[2];
    // d_in[3] = Wq, d_in[4] = Wk : unused (softmax over a single key == 1)
    const float* Wv = (const float*)d_in[5];
    const float* Wo = (const float*)d_in[6];
    const float* bw = (const float*)d_in[7];
    const float* sg = (const float*)d_in[8];
    const float* nw = (const float*)d_in[9];
    const int* isur = (const int*)d_in[10];
    float* out = (float*)d_out;

    float* ws     = (float*)d_ws;
    float* cw     = ws;                       // B*L*C  = 3072 (pad to 4096)
    float* cr     = ws + 4096;                // B*C*D  = 24576
    float* fused  = ws + 4096 + 24576;        // B*D    = 4096
    float* o      = fused + 4096;             // B*D    = 4096

    hipLaunchKernelGGL(k_cluster, dim3(BB * LL), dim3(256), 0, stream, te, Wc, cw);
    hipLaunchKernelGGL(k_creps,   dim3(BB * 32), dim3(256), 0, stream, te, cw, cr);
    hipLaunchKernelGGL(k_vfuse,   dim3(DD / 4), dim3(256), 0, stream, cr, Wv, bw, sg, isur, fused);
    hipLaunchKernelGGL(k_rmsout,  dim3(DD / 4), dim3(256), 0, stream, fused, nw, Wo, o);
    hipLaunchKernelGGL(k_add,     dim3(2048), dim3(256), 0, stream, x, o, out);
}